// Round 2
// baseline (12789.186 us; speedup 1.0000x reference)
//
#include <hip/hip_runtime.h>
#include <math.h>

#define B_  64
#define T_  2048
#define V_  512
#define H_  256
#define D_  128
#define VD_ 8

// ---------------------------------------------------------------------------
// Generic NT GEMM: C[m,n] = bias[n] + sum_k A[m,k] * B[n,k]   (unchanged R1)
// ---------------------------------------------------------------------------
__global__ __launch_bounds__(256) void gemm_nt_kernel(
    const float* __restrict__ A, const float* __restrict__ Bm,
    const float* __restrict__ bias, float* __restrict__ C,
    int M, int N, int K)
{
    __shared__ float As[32][68];
    __shared__ float Bs[32][260];

    const int m0  = blockIdx.x * 64;
    const int n0  = blockIdx.y * 256;
    const int tid = threadIdx.x;
    const int tm  = tid >> 4;
    const int tn  = tid & 15;

    float acc[4][4][4];
    #pragma unroll
    for (int i = 0; i < 4; i++)
      #pragma unroll
      for (int cb = 0; cb < 4; cb++)
        #pragma unroll
        for (int jj = 0; jj < 4; jj++) acc[i][cb][jj] = 0.f;

    for (int kc = 0; kc < K; kc += 32) {
        #pragma unroll
        for (int rep = 0; rep < 2; rep++) {
            int f  = tid + rep * 256;
            int mm = f >> 3;
            int k4 = (f & 7) << 2;
            float4 v = *(const float4*)(A + (size_t)(m0 + mm) * K + kc + k4);
            As[k4 + 0][mm] = v.x; As[k4 + 1][mm] = v.y;
            As[k4 + 2][mm] = v.z; As[k4 + 3][mm] = v.w;
        }
        #pragma unroll
        for (int rep = 0; rep < 8; rep++) {
            int f  = tid + rep * 256;
            int nn = f >> 3;
            int k4 = (f & 7) << 2;
            float4 v = *(const float4*)(Bm + (size_t)(n0 + nn) * K + kc + k4);
            Bs[k4 + 0][nn] = v.x; Bs[k4 + 1][nn] = v.y;
            Bs[k4 + 2][nn] = v.z; Bs[k4 + 3][nn] = v.w;
        }
        __syncthreads();

        #pragma unroll
        for (int kk = 0; kk < 32; kk++) {
            float4 a = *(const float4*)&As[kk][4 * tm];
            #pragma unroll
            for (int cb = 0; cb < 4; cb++) {
                float4 b = *(const float4*)&Bs[kk][64 * cb + 4 * tn];
                acc[0][cb][0] += a.x * b.x; acc[0][cb][1] += a.x * b.y;
                acc[0][cb][2] += a.x * b.z; acc[0][cb][3] += a.x * b.w;
                acc[1][cb][0] += a.y * b.x; acc[1][cb][1] += a.y * b.y;
                acc[1][cb][2] += a.y * b.z; acc[1][cb][3] += a.y * b.w;
                acc[2][cb][0] += a.z * b.x; acc[2][cb][1] += a.z * b.y;
                acc[2][cb][2] += a.z * b.z; acc[2][cb][3] += a.z * b.w;
                acc[3][cb][0] += a.w * b.x; acc[3][cb][1] += a.w * b.y;
                acc[3][cb][2] += a.w * b.z; acc[3][cb][3] += a.w * b.w;
            }
        }
        __syncthreads();
    }

    #pragma unroll
    for (int cb = 0; cb < 4; cb++) {
        int c = n0 + 64 * cb + 4 * tn;
        float4 bv;
        if (bias) bv = *(const float4*)(bias + c);
        else      bv = make_float4(0.f, 0.f, 0.f, 0.f);
        #pragma unroll
        for (int i = 0; i < 4; i++) {
            int r = m0 + 4 * tm + i;
            float4 v = make_float4(acc[i][cb][0] + bv.x, acc[i][cb][1] + bv.y,
                                   acc[i][cb][2] + bv.z, acc[i][cb][3] + bv.w);
            *(float4*)(C + (size_t)r * N + c) = v;
        }
    }
}

// ---------------------------------------------------------------------------
// W_hhsh[j][v] = sum_k W_hh[j][k] * W_sh[k][v]   (256 x 8)
// ---------------------------------------------------------------------------
__global__ __launch_bounds__(256) void whhsh_kernel(
    const float* __restrict__ W_hh, const float* __restrict__ W_sh,
    float* __restrict__ W_hhsh)
{
    int j = threadIdx.x;
    float acc[VD_];
    #pragma unroll
    for (int v = 0; v < VD_; v++) acc[v] = 0.f;
    for (int k = 0; k < H_; k += 4) {
        float4 w = *(const float4*)(W_hh + (size_t)j * H_ + k);
        const float* s0 = W_sh + (size_t)k * VD_;
        #pragma unroll
        for (int v = 0; v < VD_; v++)
            acc[v] += w.x * s0[v] + w.y * s0[VD_ + v]
                    + w.z * s0[2 * VD_ + v] + w.w * s0[3 * VD_ + v];
    }
    #pragma unroll
    for (int v = 0; v < VD_; v++) W_hhsh[j * VD_ + v] = acc[v];
}

__device__ __forceinline__ float tanh_fast(float x) {
    float e = __expf(2.f * x);          // inf-safe: x>>0 -> 1, x<<0 -> -1
    return 1.f - 2.f / (e + 1.f);
}

// ---------------------------------------------------------------------------
// Recurrence, wave-specialized. Block = 576 (9 waves) per batch element.
//   waves 0-7 : dot = W_hh @ h(t-1)  (thread (j,half), 128 FMA each)
//   wave  8   : gates(t-1) + full stack blend + sh_top, CONCURRENT with dot
// pre(t) = z(t) + b_hh + dot + W_hhsh @ stop(t-1);  2 barriers/step.
// Pipeline: iter t computes h(t); wave-8 at iter t handles gates(t-1)
// (t=1..T_), so loop runs t = 0..T_ inclusive (dot idle at t=T_).
// ---------------------------------------------------------------------------
__global__ __launch_bounds__(576) void recurrence_kernel(
    const float* __restrict__ Z,        // (B,T,H)
    const float* __restrict__ stack0,   // (B,D,VD)
    const float* __restrict__ hidden0,  // (B,H)
    const float* __restrict__ W_hh,     // (H,H)
    const float* __restrict__ b_hh,     // (H)
    const float* __restrict__ W_hhsh,   // (H,VD) precomputed
    const float* __restrict__ W_a,      // (3,H)
    const float* __restrict__ W_n,      // (VD,H)
    float* __restrict__ H_all,          // (B,T,H)
    float* __restrict__ out_stack,      // (B,D,VD)
    float* __restrict__ out_hidden)     // (B,H)
{
    const int b    = blockIdx.x;
    const int tid  = threadIdx.x;
    const bool is_dot = (tid < 512);
    const int j    = tid & 255;
    const int half = (tid >> 8) & 1;
    const int lane = tid & 63;

    __shared__ float sh_hnew[H_];
    __shared__ float sh_part[H_];
    __shared__ float sh_top[VD_];
    __shared__ float sh_st[2][D_ * VD_];

    // --- per-role preloads -------------------------------------------------
    float4 wreg[32];                    // dot threads: W_hh half-row
    float4 wsh0 = {0,0,0,0}, wsh1 = {0,0,0,0};
    float  bhh = 0.f;
    float4 wan[11];                     // wave 8: W_a/W_n fragments

    if (is_dot) {
        const float4* wrow = (const float4*)(W_hh + (size_t)j * H_ + half * 128);
        #pragma unroll
        for (int q = 0; q < 32; q++) wreg[q] = wrow[q];
        if (half == 0) {
            wsh0 = ((const float4*)(W_hhsh + j * VD_))[0];
            wsh1 = ((const float4*)(W_hhsh + j * VD_))[1];
            bhh  = b_hh[j];
        }
    } else {
        #pragma unroll
        for (int r = 0; r < 11; r++) {
            const float* src = (r < 3) ? (W_a + r * H_) : (W_n + (r - 3) * H_);
            wan[r] = *(const float4*)(src + 4 * lane);
        }
    }

    // --- LDS init ----------------------------------------------------------
    for (int q = tid; q < D_ * VD_; q += 576)
        sh_st[0][q] = stack0[(size_t)b * D_ * VD_ + q];
    if (tid < H_)  sh_hnew[tid] = hidden0[(size_t)b * H_ + tid];
    if (tid < VD_) sh_top[tid]  = stack0[(size_t)b * D_ * VD_ + tid];
    __syncthreads();

    float z_cur = 0.f, z_nxt = 0.f, hidden_reg = 0.f;
    if (is_dot && half == 0)
        z_cur = Z[((size_t)b * T_) * H_ + j];

    int p = 0;

    for (int t = 0; t <= T_; t++) {
        float partial = 0.f;

        // ---- phase 1: dot (waves 0-7) || gates+blend (wave 8) ------------
        if (is_dot) {
            if (t < T_) {
                if (half == 0 && t + 1 < T_)
                    z_nxt = Z[((size_t)b * T_ + t + 1) * H_ + j];
                const float4* hh = (const float4*)&sh_hnew[half * 128];
                float p0 = 0.f, p1 = 0.f, p2 = 0.f, p3 = 0.f;
                #pragma unroll
                for (int q = 0; q < 32; q += 4) {
                    float4 h0 = hh[q+0], h1 = hh[q+1], h2 = hh[q+2], h3 = hh[q+3];
                    p0 += h0.x*wreg[q+0].x + h0.y*wreg[q+0].y + h0.z*wreg[q+0].z + h0.w*wreg[q+0].w;
                    p1 += h1.x*wreg[q+1].x + h1.y*wreg[q+1].y + h1.z*wreg[q+1].z + h1.w*wreg[q+1].w;
                    p2 += h2.x*wreg[q+2].x + h2.y*wreg[q+2].y + h2.z*wreg[q+2].z + h2.w*wreg[q+2].w;
                    p3 += h3.x*wreg[q+3].x + h3.y*wreg[q+3].y + h3.z*wreg[q+3].z + h3.w*wreg[q+3].w;
                }
                partial = (p0 + p1) + (p2 + p3);
                if (half) sh_part[j] = partial;
            }
        } else if (t > 0) {
            // gates(t-1) from sh_hnew = h(t-1)
            float4 h4 = *(const float4*)&sh_hnew[4 * lane];
            float acc[11];
            #pragma unroll
            for (int r = 0; r < 11; r++)
                acc[r] = h4.x*wan[r].x + h4.y*wan[r].y + h4.z*wan[r].z + h4.w*wan[r].w;
            #pragma unroll
            for (int off = 1; off < 64; off <<= 1)
                #pragma unroll
                for (int r = 0; r < 11; r++)
                    acc[r] += __shfl_xor(acc[r], off, 64);
            // every lane now owns all 11 sums
            float m  = fmaxf(acc[0], fmaxf(acc[1], acc[2]));
            float e0 = __expf(acc[0]-m), e1 = __expf(acc[1]-m), e2 = __expf(acc[2]-m);
            float inv = 1.f / (e0 + e1 + e2);
            float a0 = e0*inv, a1 = e1*inv, a2 = e2*inv;
            float nv[VD_];
            #pragma unroll
            for (int v = 0; v < VD_; v++)
                nv[v] = 1.f / (1.f + __expf(-acc[3 + v]));

            // stack blend: lane owns elements [16*lane .. 16*lane+15]
            const float* st = sh_st[p];
            int base = 16 * lane;
            float4 o0 = *(const float4*)&st[base+0], o1 = *(const float4*)&st[base+4];
            float4 o2 = *(const float4*)&st[base+8], o3 = *(const float4*)&st[base+12];
            int poff = (lane == 0)  ? 0 : base - 8;     // prev lane's upper 8
            int noff = (lane == 63) ? 0 : base + 16;    // next lane's lower 8
            float4 pu0 = *(const float4*)&st[poff+0], pu1 = *(const float4*)&st[poff+4];
            float4 nx0 = *(const float4*)&st[noff+0], nx1 = *(const float4*)&st[noff+4];
            float own[16] = {o0.x,o0.y,o0.z,o0.w, o1.x,o1.y,o1.z,o1.w,
                             o2.x,o2.y,o2.z,o2.w, o3.x,o3.y,o3.z,o3.w};
            float pu[8]  = {pu0.x,pu0.y,pu0.z,pu0.w, pu1.x,pu1.y,pu1.z,pu1.w};
            float nx[8]  = {nx0.x,nx0.y,nx0.z,nx0.w, nx1.x,nx1.y,nx1.z,nx1.w};
            float nw[16];
            #pragma unroll
            for (int e = 0; e < 16; e++) {
                float push = (e < 8) ? ((lane == 0) ? nv[e] : pu[e]) : own[e - 8];
                float pop  = (e < 8) ? own[e + 8]
                                     : ((lane == 63) ? 0.f : nx[e - 8]);
                nw[e] = a0 * push + a1 * pop + a2 * own[e];
            }
            if (t < T_) {
                float* dst = sh_st[p ^ 1];
                *(float4*)&dst[base+0]  = make_float4(nw[0],nw[1],nw[2],nw[3]);
                *(float4*)&dst[base+4]  = make_float4(nw[4],nw[5],nw[6],nw[7]);
                *(float4*)&dst[base+8]  = make_float4(nw[8],nw[9],nw[10],nw[11]);
                *(float4*)&dst[base+12] = make_float4(nw[12],nw[13],nw[14],nw[15]);
                if (lane == 0) {
                    *(float4*)&sh_top[0] = make_float4(nw[0],nw[1],nw[2],nw[3]);
                    *(float4*)&sh_top[4] = make_float4(nw[4],nw[5],nw[6],nw[7]);
                }
            } else {
                float* dst = out_stack + (size_t)b * D_ * VD_ + base;
                *(float4*)&dst[0]  = make_float4(nw[0],nw[1],nw[2],nw[3]);
                *(float4*)&dst[4]  = make_float4(nw[4],nw[5],nw[6],nw[7]);
                *(float4*)&dst[8]  = make_float4(nw[8],nw[9],nw[10],nw[11]);
                *(float4*)&dst[12] = make_float4(nw[12],nw[13],nw[14],nw[15]);
            }
            p ^= 1;
        }
        __syncthreads();   // barrier 1: sh_part + sh_top(t-1) ready

        // ---- phase 2: combine + tanh (waves 0-3) -------------------------
        if (is_dot && t < T_ && half == 0) {
            float pre = z_cur + bhh + partial + sh_part[j];
            float4 s0 = *(const float4*)&sh_top[0];
            float4 s1 = *(const float4*)&sh_top[4];
            pre += wsh0.x*s0.x + wsh0.y*s0.y + wsh0.z*s0.z + wsh0.w*s0.w
                 + wsh1.x*s1.x + wsh1.y*s1.y + wsh1.z*s1.z + wsh1.w*s1.w;
            float hn = tanh_fast(pre);
            hidden_reg = hn;
            sh_hnew[j] = hn;
            H_all[((size_t)b * T_ + t) * H_ + j] = hn;
            z_cur = z_nxt;
        }
        __syncthreads();   // barrier 2: h(t) visible
    }

    if (is_dot && half == 0)
        out_hidden[(size_t)b * H_ + j] = hidden_reg;
}

extern "C" void kernel_launch(void* const* d_in, const int* in_sizes, int n_in,
                              void* d_out, int out_size, void* d_ws, size_t ws_size,
                              hipStream_t stream) {
    const float* inputs  = (const float*)d_in[0];
    const float* stack0  = (const float*)d_in[1];
    const float* hidden0 = (const float*)d_in[2];
    const float* W_ih    = (const float*)d_in[3];
    const float* b_ih    = (const float*)d_in[4];
    const float* W_hh    = (const float*)d_in[5];
    const float* b_hh    = (const float*)d_in[6];
    const float* W_sh    = (const float*)d_in[7];
    const float* W_y     = (const float*)d_in[8];
    const float* W_a     = (const float*)d_in[9];
    const float* W_n     = (const float*)d_in[10];

    float* out = (float*)d_out;
    // Z + W_hhsh staged in d_out (consumed before post-GEMM overwrites).
    float* Z       = out;                                 // (B,T,H)
    float* W_hhsh  = out + (size_t)B_ * T_ * H_;          // (H,VD)
    float* H_all   = (float*)d_ws;                        // (B,T,H)
    float* out_stack  = out + (size_t)B_ * T_ * V_;
    float* out_hidden = out_stack + (size_t)B_ * D_ * VD_;

    const int M = B_ * T_;   // 131072

    gemm_nt_kernel<<<dim3(M / 64, H_ / 256), 256, 0, stream>>>(
        inputs, W_ih, b_ih, Z, M, H_, V_);

    whhsh_kernel<<<1, 256, 0, stream>>>(W_hh, W_sh, W_hhsh);

    recurrence_kernel<<<dim3(B_), 576, 0, stream>>>(
        Z, stack0, hidden0, W_hh, b_hh, W_hhsh, W_a, W_n,
        H_all, out_stack, out_hidden);

    gemm_nt_kernel<<<dim3(M / 64, V_ / 256), 256, 0, stream>>>(
        H_all, W_y, nullptr, out, M, V_, H_);
}